// Round 14
// baseline (666.527 us; speedup 1.0000x reference)
//
#include <hip/hip_runtime.h>
#include <hip/hip_bf16.h>

#define T   512
#define D   256
#define H   4
#define NN  8192
#define V   256
#define EPSF 1e-5f
#define QKS 8          // split-K for scores GEMM (128² tiles)
#define DSPLIT 32      // split-K for decoder GEMM (128² tiles)
#define N_LAYER 6

typedef __bf16 bf16;
typedef __attribute__((__ext_vector_type__(8))) __bf16 bf16x8;
typedef __attribute__((__ext_vector_type__(4))) __bf16 bf16x4;
typedef __attribute__((__ext_vector_type__(4))) float  f32x4;

#define MFMA16(a, b, c) __builtin_amdgcn_mfma_f32_16x16x32_bf16((a), (b), (c), 0, 0, 0)
// async global->LDS, 16B per lane; LDS dest is wave-uniform base + lane*16
#define GLD16(g, l)                                                         \
    __builtin_amdgcn_global_load_lds(                                       \
        (const __attribute__((address_space(1))) void*)(g),                 \
        (__attribute__((address_space(3))) void*)(l), 16, 0, 0)

// ---------------- block-wide sum over 256 threads ---------------------------
__device__ __forceinline__ float blk_sum256(float v, float* red) {
#pragma unroll
    for (int off = 32; off > 0; off >>= 1) v += __shfl_down(v, off, 64);
    int lane = threadIdx.x & 63, w = threadIdx.x >> 6;
    __syncthreads();
    if (lane == 0) red[w] = v;
    __syncthreads();
    return red[0] + red[1] + red[2] + red[3];
}

// ---------------- transpose + f32->bf16 convert (32x32 tiles) ---------------
__global__ __launch_bounds__(256) void tcvt_k(const float* __restrict__ in,
                                              bf16* __restrict__ out, int R, int C) {
    __shared__ float t[32][33];
    size_t hoff = (size_t)blockIdx.z * R * C;
    int c0 = blockIdx.x * 32, r0 = blockIdx.y * 32;
    int x = threadIdx.x & 31, y = threadIdx.x >> 5;
#pragma unroll
    for (int p = 0; p < 4; ++p)
        t[y + 8 * p][x] = in[hoff + (size_t)(r0 + y + 8 * p) * C + c0 + x];
    __syncthreads();
#pragma unroll
    for (int p = 0; p < 4; ++p)
        out[hoff + (size_t)(c0 + y + 8 * p) * R + r0 + x] = (bf16)t[x][y + 8 * p];
}

// ---------------- RoPE cos/sin HALF tables (pairs share angle) --------------
__global__ __launch_bounds__(256) void rope_tab_k(bf16* __restrict__ cosH,
                                                  bf16* __restrict__ sinH) {
    int k = blockIdx.x * 256 + threadIdx.x;     // 0..NN/2-1
    int t = blockIdx.y;
    float q = (float)(2 * k);
    float f = exp2f(q * (-16.0f / (float)NN)) * 0.15915494309189535f;
    float u = fmodf((float)t * f, 1.0f);
    float a = u * 6.283185307179586f;
    cosH[(size_t)t * (NN / 2) + k] = (bf16)cosf(a);
    sinH[(size_t)t * (NN / 2) + k] = (bf16)sinf(a);
}

// ---------------- x = LN(embed[idx]) (writes f32 + bf16 + bf16^T) -----------
__global__ __launch_bounds__(256) void embed_ln_k(const int* __restrict__ idx,
                                                  const float* __restrict__ embed,
                                                  float* __restrict__ x,
                                                  bf16* __restrict__ xb,
                                                  bf16* __restrict__ xbT) {
    __shared__ float red[4];
    int t = blockIdx.x, d = threadIdx.x;
    float e = embed[(size_t)idx[t] * D + d];
    float m = blk_sum256(e, red) * (1.0f / D);
    float df = e - m;
    float vv = blk_sum256(df * df, red) * (1.0f / D);
    float r = df * rsqrtf(vv + EPSF);
    x[(size_t)t * D + d] = r;
    xb[(size_t)t * D + d] = (bf16)r;
    xbT[(size_t)d * T + t] = (bf16)r;
}

// ---------------- MFMA 64x64 core v2: BK=64, 2-phase gload_lds pipeline -----
// (R7-proven, verbatim) A row-major [m][k] (lda), B as rows of B^T [n][k].
__device__ __forceinline__ void gemm_core64(const bf16* __restrict__ Ap, size_t lda,
                                            const bf16* __restrict__ Bp, size_t ldb,
                                            int ksteps, bf16* lds,
                                            f32x4 acc[2][2], int tid) {
    int lane = tid & 63, wid = tid >> 6;
    int wr = (wid >> 1) * 32, wc = (wid & 1) * 32;
    int fr = lane & 15, s = lane >> 4;
    int srow = wid * 16 + (lane >> 3);
    int sx   = ((lane & 7) ^ (srow & 7)) * 8;      // inverse-swizzled src elem
    const bf16* ag = Ap + (size_t)srow * lda + sx;
    const bf16* bg = Bp + (size_t)srow * ldb + sx;
    bf16* a_w = lds + wid * 1024;                  // wave-uniform dests
    bf16* b_w = lds + 8192 + wid * 1024;
    int ar = wr + fr, br = wc + fr;
    int aoff0 = ar * 128 + (((s)     ^ (ar & 7)) << 4);
    int aoff1 = ar * 128 + (((4 + s) ^ (ar & 7)) << 4);
    int boff0 = br * 128 + (((s)     ^ (br & 7)) << 4);
    int boff1 = br * 128 + (((4 + s) ^ (br & 7)) << 4);
    GLD16(ag, a_w);  GLD16(ag + 8 * lda, a_w + 512);
    GLD16(bg, b_w);  GLD16(bg + 8 * ldb, b_w + 512);
    __syncthreads();
    for (int ks = 0; ks < ksteps; ++ks) {
        int cur = ks & 1;
        if (ks + 1 < ksteps) {                     // issue-early: overlap w/ MFMA
            int nxt = cur ^ 1;
            size_t ko = (size_t)(ks + 1) * 64;
            bf16* an = lds + nxt * 4096 + wid * 1024;
            bf16* bn = lds + 8192 + nxt * 4096 + wid * 1024;
            GLD16(ag + ko, an);  GLD16(ag + ko + 8 * lda, an + 512);
            GLD16(bg + ko, bn);  GLD16(bg + ko + 8 * ldb, bn + 512);
        }
        const char* cA = (const char*)(lds + cur * 4096);
        const char* cB = (const char*)(lds + 8192 + cur * 4096);
        bf16x8 a00 = *(const bf16x8*)(cA + aoff0);
        bf16x8 a01 = *(const bf16x8*)(cA + aoff1);
        bf16x8 a10 = *(const bf16x8*)(cA + aoff0 + 2048);  // row +16
        bf16x8 a11 = *(const bf16x8*)(cA + aoff1 + 2048);
        bf16x8 b00 = *(const bf16x8*)(cB + boff0);
        bf16x8 b01 = *(const bf16x8*)(cB + boff1);
        bf16x8 b10 = *(const bf16x8*)(cB + boff0 + 2048);
        bf16x8 b11 = *(const bf16x8*)(cB + boff1 + 2048);
        acc[0][0] = MFMA16(a00, b00, acc[0][0]);
        acc[0][0] = MFMA16(a01, b01, acc[0][0]);
        acc[0][1] = MFMA16(a00, b10, acc[0][1]);
        acc[0][1] = MFMA16(a01, b11, acc[0][1]);
        acc[1][0] = MFMA16(a10, b00, acc[1][0]);
        acc[1][0] = MFMA16(a11, b01, acc[1][0]);
        acc[1][1] = MFMA16(a10, b10, acc[1][1]);
        acc[1][1] = MFMA16(a11, b11, acc[1][1]);
        __syncthreads();   // drains next-tile vmcnt + WAR on cur buffer
    }
}

// ======== 128x128 MFMA core v2 — core64 algebra extended to 128 rows ========
// (R13-proven) BK=64, 4 waves (2x2 of 64x64), same swizzle (key = fr&7).
// LDS: A[2][128][64] bf16 (32KB) at 0, B same at elem 16384. Total 64KB.
__device__ __forceinline__ void gemm_core128v2(const bf16* __restrict__ Ap, size_t lda,
                                               const bf16* __restrict__ Bp, size_t ldb,
                                               int ksteps, bf16* lds,
                                               f32x4 acc[4][4], int tid) {
    int lane = tid & 63, wid = tid >> 6;
    int wr = (wid >> 1) * 64, wc = (wid & 1) * 64;
    int fr = lane & 15, s = lane >> 4;
    int srow = wid * 16 + (lane >> 3);             // rows 16w..16w+7 (+8, +64, +72)
    int sx   = ((lane & 7) ^ (srow & 7)) * 8;      // inverse-swizzled src elem
    const bf16* ag = Ap + (size_t)srow * lda + sx; // (srow+64)&7 == srow&7: same sx
    const bf16* bg = Bp + (size_t)srow * ldb + sx;
    bf16* a_w = lds + wid * 1024;                  // wave-uniform dests (elems)
    bf16* b_w = lds + 16384 + wid * 1024;
    int ar = wr + fr, br = wc + fr;                // (ar&7) == (fr&7)
    int aoff0 = (ar & 63) * 128 + (((s)     ^ (fr & 7)) << 4) + (wr >> 6) * 8192;
    int aoff1 = (ar & 63) * 128 + (((4 + s) ^ (fr & 7)) << 4) + (wr >> 6) * 8192;
    int boff0 = (br & 63) * 128 + (((s)     ^ (fr & 7)) << 4) + (wc >> 6) * 8192;
    int boff1 = (br & 63) * 128 + (((4 + s) ^ (fr & 7)) << 4) + (wc >> 6) * 8192;
    // prologue: stage kstep 0 into buffer 0
    GLD16(ag, a_w);                 GLD16(ag + 8 * lda, a_w + 512);
    GLD16(ag + 64 * lda, a_w + 4096); GLD16(ag + 72 * lda, a_w + 4608);
    GLD16(bg, b_w);                 GLD16(bg + 8 * ldb, b_w + 512);
    GLD16(bg + 64 * ldb, b_w + 4096); GLD16(bg + 72 * ldb, b_w + 4608);
    __syncthreads();
    for (int ks = 0; ks < ksteps; ++ks) {
        int cur = ks & 1;
        if (ks + 1 < ksteps) {                     // issue-early: overlap w/ MFMA
            int nxt = cur ^ 1;
            size_t ko = (size_t)(ks + 1) * 64;
            bf16* an = lds + nxt * 8192 + wid * 1024;
            bf16* bn = lds + 16384 + nxt * 8192 + wid * 1024;
            GLD16(ag + ko, an);                 GLD16(ag + ko + 8 * lda, an + 512);
            GLD16(ag + ko + 64 * lda, an + 4096); GLD16(ag + ko + 72 * lda, an + 4608);
            GLD16(bg + ko, bn);                 GLD16(bg + ko + 8 * ldb, bn + 512);
            GLD16(bg + ko + 64 * ldb, bn + 4096); GLD16(bg + ko + 72 * ldb, bn + 4608);
        }
        const char* cA = (const char*)(lds + cur * 8192);
        const char* cB = (const char*)(lds + 16384 + cur * 8192);
        bf16x8 a0[4], a1[4], b0[4], b1[4];
#pragma unroll
        for (int i = 0; i < 4; ++i) {
            a0[i] = *(const bf16x8*)(cA + aoff0 + i * 2048);   // row +16 each
            a1[i] = *(const bf16x8*)(cA + aoff1 + i * 2048);
            b0[i] = *(const bf16x8*)(cB + boff0 + i * 2048);
            b1[i] = *(const bf16x8*)(cB + boff1 + i * 2048);
        }
#pragma unroll
        for (int i = 0; i < 4; ++i)
#pragma unroll
            for (int j = 0; j < 4; ++j) {
                acc[i][j] = MFMA16(a0[i], b0[j], acc[i][j]);
                acc[i][j] = MFMA16(a1[i], b1[j], acc[i][j]);
            }
        __syncthreads();   // drains next-tile vmcnt + WAR on cur buffer
    }
}

// ---------------- encoder GEMM + relu (+RoPE / *old), 128x128 v2 core -------
// (R13-proven verbatim) MODE 0: xs=relu(C), qr=rope(xs). MODE 1: xs*=relu(C)
template <int MODE>
__global__ __launch_bounds__(256) void enc_mfma_k(const bf16* __restrict__ A,
                                                  const bf16* __restrict__ Wt,
                                                  bf16* __restrict__ xs,
                                                  bf16* __restrict__ qr,
                                                  const bf16* __restrict__ cosH,
                                                  const bf16* __restrict__ sinH,
                                                  int aHeadStride) {
    __shared__ __align__(16) bf16 smem[32768];     // 64 KB
    int h = blockIdx.z;
    int row0 = blockIdx.y * 128, col0 = blockIdx.x * 128;
    const bf16* Ap = A + (size_t)h * aHeadStride + (size_t)row0 * D;
    const bf16* Bp = Wt + ((size_t)h * NN + col0) * D;
    int tid = threadIdx.x;
    f32x4 acc[4][4];
#pragma unroll
    for (int i = 0; i < 4; ++i)
#pragma unroll
        for (int j = 0; j < 4; ++j) acc[i][j] = f32x4{0.f, 0.f, 0.f, 0.f};
    gemm_core128v2(Ap, D, Bp, D, D / 64, smem, acc, tid);

    int lane = tid & 63, wid = tid >> 6;
    int wr = (wid >> 1) * 64, wc = (wid & 1) * 64;
    int fr = lane & 15, fq = lane >> 4;
#pragma unroll
    for (int mi = 0; mi < 4; ++mi)
#pragma unroll
        for (int ni = 0; ni < 4; ++ni)
#pragma unroll
            for (int j = 0; j < 4; ++j) {
                int m = row0 + wr + mi * 16 + fq * 4 + j;
                int n = col0 + wc + ni * 16 + fr;
                size_t base = ((size_t)h * T + m) * NN + n;
                float v = fmaxf((float)acc[mi][ni][j], 0.0f);
                if (MODE == 0) {
                    float p = __shfl_xor(v, 1, 64);   // partner col n^1
                    float cs = (float)cosH[(size_t)m * (NN / 2) + (n >> 1)];
                    float sn = (float)sinH[(size_t)m * (NN / 2) + (n >> 1)];
                    float qv = v * cs + ((n & 1) ? p * sn : -p * sn);
                    xs[base] = (bf16)v;
                    qr[base] = (bf16)qv;
                } else {
                    float xo = (float)xs[base];
                    xs[base] = (bf16)(xo * v);
                }
            }
}

// ---------------- scores GEMM: spartb[ks][h][t][s] bf16, 128² lower-tri -----
// 1-D grid, 320 blocks: g = bid%32 = (h,ksplit) group; p = bid/32 -> (ti,tj)
__global__ __launch_bounds__(256) void qq_mfma_k(const bf16* __restrict__ qrb,
                                                 bf16* __restrict__ spartb) {
    __shared__ __align__(16) bf16 smem[32768];
    static const int TI[10] = {0,1,1,2,2,2,3,3,3,3};
    static const int TJ[10] = {0,0,1,0,1,2,0,1,2,3};
    int g = blockIdx.x & 31;
    int h = g >> 3, ksplit = g & 7;
    int p = blockIdx.x >> 5;          // 0..9
    int ti = TI[p], tj = TJ[p];
    const bf16* Q = qrb + (size_t)h * T * NN + (size_t)ksplit * (NN / QKS);
    const bf16* Ap = Q + (size_t)(ti * 128) * NN;
    const bf16* Bp = Q + (size_t)(tj * 128) * NN;
    int tid = threadIdx.x;
    f32x4 acc[4][4];
#pragma unroll
    for (int i = 0; i < 4; ++i)
#pragma unroll
        for (int j = 0; j < 4; ++j) acc[i][j] = f32x4{0.f, 0.f, 0.f, 0.f};
    gemm_core128v2(Ap, NN, Bp, NN, (NN / QKS) / 64, smem, acc, tid);

    int lane = tid & 63, wid = tid >> 6;
    int wr = (wid >> 1) * 64, wc = (wid & 1) * 64;
    int fr = lane & 15, fq = lane >> 4;
    bf16* outp = spartb + (size_t)(ksplit * H + h) * T * T;
#pragma unroll
    for (int mi = 0; mi < 4; ++mi)
#pragma unroll
        for (int ni = 0; ni < 4; ++ni) {
            int s = tj * 128 + wc + ni * 16 + fr;
            int mbase = ti * 128 + wr + mi * 16 + fq * 4;
#pragma unroll
            for (int j = 0; j < 4; ++j)
                outp[(size_t)(mbase + j) * T + s] = (bf16)acc[mi][ni][j];
        }
}

// ---------------- sb[h][t][s] = bf16(sum_ks spartb), strict causal mask -----
__global__ __launch_bounds__(256) void mask_cvt_k(const bf16* __restrict__ spartb,
                                                  bf16* __restrict__ sb) {
    int t = blockIdx.x * 2 + (threadIdx.x >> 7);
    int h = blockIdx.y;
    int l = threadIdx.x & 127;
    int s = l * 4;
    const bf16* s0 = spartb + ((size_t)h * T + t) * T + s;
    const size_t st = (size_t)H * T * T;
    float a0 = 0, a1 = 0, a2 = 0, a3 = 0;
#pragma unroll
    for (int k = 0; k < QKS; ++k) {
        bf16x4 w = *(const bf16x4*)(s0 + k * st);
        a0 += (float)w[0]; a1 += (float)w[1]; a2 += (float)w[2]; a3 += (float)w[3];
    }
    bf16x4 o;
    o[0] = (bf16)((s + 0 < t) ? a0 : 0.0f);
    o[1] = (bf16)((s + 1 < t) ? a1 : 0.0f);
    o[2] = (bf16)((s + 2 < t) ? a2 : 0.0f);
    o[3] = (bf16)((s + 3 < t) ? a3 : 0.0f);
    *(bf16x4*)(sb + ((size_t)h * T + t) * T + s) = o;
}

// ---------------- av: ykv_pre[h][t][d] = sum_s sb[t,s] * x[s,d] (MFMA) ------
__global__ __launch_bounds__(256) void av_mfma_k(const bf16* __restrict__ sb,
                                                 const bf16* __restrict__ xbT,
                                                 float* __restrict__ ykv_pre) {
    __shared__ __align__(16) char smem[32768];
    int h = blockIdx.z;
    int ti = blockIdx.y;
    int row0 = ti * 64, col0 = blockIdx.x * 64;
    const bf16* Ap = sb + ((size_t)h * T + row0) * T;
    const bf16* Bp = xbT + (size_t)col0 * T;
    int tid = threadIdx.x;
    f32x4 acc[2][2];
#pragma unroll
    for (int i = 0; i < 2; ++i)
#pragma unroll
        for (int j = 0; j < 2; ++j) acc[i][j] = f32x4{0.f, 0.f, 0.f, 0.f};
    // causal: sb[t][s]==0 for s>=t, so only need k < (ti+1)*64
    gemm_core64(Ap, T, Bp, T, ti + 1, (bf16*)smem, acc, tid);

    int lane = tid & 63, wid = tid >> 6;
    int wr = (wid >> 1) * 32, wc = (wid & 1) * 32;
    int fr = lane & 15, fq = lane >> 4;
#pragma unroll
    for (int mi = 0; mi < 2; ++mi)
#pragma unroll
        for (int ni = 0; ni < 2; ++ni) {
            int n = col0 + wc + ni * 16 + fr;
            int mbase = row0 + wr + mi * 16 + fq * 4;
#pragma unroll
            for (int j = 0; j < 4; ++j)
                ykv_pre[((size_t)h * T + (mbase + j)) * D + n] = acc[mi][ni][j];
        }
}

// ---------------- ykv LN: ykvb = LN(ykv_pre) --------------------------------
__global__ __launch_bounds__(256) void ykv_ln_k(const float* __restrict__ ykv_pre,
                                                bf16* __restrict__ ykvb) {
    __shared__ float red[4];
    int t = blockIdx.x, h = blockIdx.y, d = threadIdx.x;
    float a = ykv_pre[((size_t)h * T + t) * D + d];
    float m = blk_sum256(a, red) * (1.0f / D);
    float df = a - m;
    float vv = blk_sum256(df * df, red) * (1.0f / D);
    ykvb[((size_t)h * T + t) * D + d] = (bf16)(df * rsqrtf(vv + EPSF));
}

// ---------------- decoder GEMM (split-K=32, 128² v2 core) -------------------
// 1-D grid, 256 blocks: ks = bid%32; t = bid/32 -> col0=(t&1)*128, row0=(t>>1)*128
__global__ __launch_bounds__(256) void dec_mfma_k(const bf16* __restrict__ xyb,
                                                  const bf16* __restrict__ decT,
                                                  float* __restrict__ ypart) {
    __shared__ __align__(16) bf16 smem[32768];
    int ks = blockIdx.x & 31;
    int t  = blockIdx.x >> 5;          // 0..7
    int col0 = (t & 1) * 128, row0 = (t >> 1) * 128;
    int cbeg = ks * ((H * NN) / DSPLIT);   // 1024-wide slices, within one head
    int h = cbeg >> 13, n0 = cbeg & (NN - 1);
    const bf16* Ap = xyb + ((size_t)h * T + row0) * NN + n0;
    const bf16* Bp = decT + (size_t)col0 * (H * NN) + cbeg;
    int tid = threadIdx.x;
    f32x4 acc[4][4];
#pragma unroll
    for (int i = 0; i < 4; ++i)
#pragma unroll
        for (int j = 0; j < 4; ++j) acc[i][j] = f32x4{0.f, 0.f, 0.f, 0.f};
    gemm_core128v2(Ap, NN, Bp, H * NN, (H * NN / DSPLIT) / 64, smem, acc, tid);

    int lane = tid & 63, wid = tid >> 6;
    int wr = (wid >> 1) * 64, wc = (wid & 1) * 64;
    int fr = lane & 15, fq = lane >> 4;
#pragma unroll
    for (int mi = 0; mi < 4; ++mi)
#pragma unroll
        for (int ni = 0; ni < 4; ++ni) {
            int n = col0 + wc + ni * 16 + fr;
            int mbase = row0 + wr + mi * 16 + fq * 4;
#pragma unroll
            for (int j = 0; j < 4; ++j)
                ypart[((size_t)ks * T + (mbase + j)) * D + n] = acc[mi][ni][j];
        }
}

// ---------------- y = LN(sum ypart); x = LN(x + y); bf16 + bf16^T copies ----
__global__ __launch_bounds__(256) void final_ln_k(const float* __restrict__ ypart,
                                                  float* __restrict__ x,
                                                  bf16* __restrict__ xb,
                                                  bf16* __restrict__ xbT) {
    __shared__ float red[4];
    int t = blockIdx.x, d = threadIdx.x;
    float ys = 0.0f;
#pragma unroll 8
    for (int ks = 0; ks < DSPLIT; ++ks) ys += ypart[((size_t)ks * T + t) * D + d];
    float m = blk_sum256(ys, red) * (1.0f / D);
    float df = ys - m;
    float vv = blk_sum256(df * df, red) * (1.0f / D);
    float yln = df * rsqrtf(vv + EPSF);
    float val = x[(size_t)t * D + d] + yln;
    float m2 = blk_sum256(val, red) * (1.0f / D);
    float df2 = val - m2;
    float v2 = blk_sum256(df2 * df2, red) * (1.0f / D);
    float r = df2 * rsqrtf(v2 + EPSF);
    x[(size_t)t * D + d] = r;
    xb[(size_t)t * D + d] = (bf16)r;
    xbT[(size_t)d * T + t] = (bf16)r;
}

// ---------------- logits = x @ lm_head (f32) --------------------------------
__global__ __launch_bounds__(256) void logits_k(const float* __restrict__ x,
                                                const float* __restrict__ lm,
                                                float* __restrict__ out) {
    int t = blockIdx.x, v = threadIdx.x;
    float a = 0.0f;
    for (int d = 0; d < D; ++d)
        a = fmaf(x[(size_t)t * D + d], lm[(size_t)d * V + v], a);
    out[(size_t)t * V + v] = a;
}

extern "C" void kernel_launch(void* const* d_in, const int* in_sizes, int n_in,
                              void* d_out, int out_size, void* d_ws, size_t ws_size,
                              hipStream_t stream) {
    const int*   idx       = (const int*)d_in[0];
    const float* embed     = (const float*)d_in[1];
    const float* encoder   = (const float*)d_in[2];
    const float* encoder_v = (const float*)d_in[3];
    const float* decoder   = (const float*)d_in[4];
    const float* lm_head   = (const float*)d_in[5];
    float* out = (float*)d_out;

    // ---- workspace layout (146.8 MB — identical to passing R12/R13) ----
    char* W = (char*)d_ws;
    float* x       = (float*)W; W += (size_t)T * D * 4;
    float* scratch = (float*)W; W += (size_t)4 * H * T * T * 4;  // 16.78MB union:
    // spartb bf16 [QKS=8][H][T][T] = 16.78MB / ypart f32 [32][T][D] = 16.78MB / ykv_pre
    bf16* xb    = (bf16*)W; W += (size_t)T * D * 2;
    bf16* xbT   = (bf16*)W; W += (size_t)D * T * 2;
    bf16* sb    = (bf16*)W; W += (size_t)H * T * T * 2;
    bf16* ykvb  = (bf16*)W; W += (size_t)H * T * D * 2;
    bf16* encT  = (bf16*)W; W += (size_t)H * NN * D * 2;
    bf16* encVT = (bf16*)W; W += (size_t)H * NN * D * 2;
    bf16* decT  = (bf16*)W; W += (size_t)D * H * NN * 2;
    bf16* cosH  = (bf16*)W; W += (size_t)T * (NN / 2) * 2;
    bf16* sinH  = (bf16*)W; W += (size_t)T * (NN / 2) * 2;
    bf16* xs    = (bf16*)W; W += (size_t)H * T * NN * 2;
    bf16* qr    = (bf16*)W; W += (size_t)H * T * NN * 2;
    bf16* spartb = (bf16*)scratch;   // bf16 alias of the scratch union

    // ---- one-time per launch: weight transpose+convert, RoPE tables ----
    tcvt_k<<<dim3(NN / 32, D / 32, H), 256, 0, stream>>>(encoder, encT, D, NN);
    tcvt_k<<<dim3(NN / 32, D / 32, H), 256, 0, stream>>>(encoder_v, encVT, D, NN);
    tcvt_k<<<dim3(D / 32, (H * NN) / 32, 1), 256, 0, stream>>>(decoder, decT, H * NN, D);
    rope_tab_k<<<dim3((NN / 2) / 256, T), 256, 0, stream>>>(cosH, sinH);

    embed_ln_k<<<T, 256, 0, stream>>>(idx, embed, x, xb, xbT);

    for (int layer = 0; layer < N_LAYER; ++layer) {
        enc_mfma_k<0><<<dim3(NN / 128, T / 128, H), 256, 0, stream>>>(
            xb, encT, xs, qr, cosH, sinH, 0);
        qq_mfma_k<<<320, 256, 0, stream>>>(qr, spartb);
        mask_cvt_k<<<dim3(T / 2, H), 256, 0, stream>>>(spartb, sb);
        av_mfma_k<<<dim3(D / 64, T / 64, H), 256, 0, stream>>>(sb, xbT, scratch);
        ykv_ln_k<<<dim3(T, H), 256, 0, stream>>>(scratch, ykvb);
        enc_mfma_k<1><<<dim3(NN / 128, T / 128, H), 256, 0, stream>>>(
            ykvb, encVT, xs, nullptr, nullptr, nullptr, T * D);
        dec_mfma_k<<<256, 256, 0, stream>>>(xs, decT, scratch);
        final_ln_k<<<T, 256, 0, stream>>>(scratch, x, xb, xbT);
    }

    logits_k<<<T, 256, 0, stream>>>(x, lm_head, out);
}

// Round 15
// 643.074 us; speedup vs baseline: 1.0365x; 1.0365x over previous
//
#include <hip/hip_runtime.h>
#include <hip/hip_bf16.h>

#define T   512
#define D   256
#define H   4
#define NN  8192
#define V   256
#define EPSF 1e-5f
#define QKS 4          // split-K for scores GEMM
#define DSPLIT 16      // split-K for decoder GEMM
#define N_LAYER 6

typedef __bf16 bf16;
typedef __attribute__((__ext_vector_type__(8))) __bf16 bf16x8;
typedef __attribute__((__ext_vector_type__(4))) __bf16 bf16x4;
typedef __attribute__((__ext_vector_type__(4))) float  f32x4;

#define MFMA16(a, b, c) __builtin_amdgcn_mfma_f32_16x16x32_bf16((a), (b), (c), 0, 0, 0)
// async global->LDS, 16B per lane; LDS dest is wave-uniform base + lane*16
#define GLD16(g, l)                                                         \
    __builtin_amdgcn_global_load_lds(                                       \
        (const __attribute__((address_space(1))) void*)(g),                 \
        (__attribute__((address_space(3))) void*)(l), 16, 0, 0)

// ---------------- block-wide sum over 256 threads ---------------------------
__device__ __forceinline__ float blk_sum256(float v, float* red) {
#pragma unroll
    for (int off = 32; off > 0; off >>= 1) v += __shfl_down(v, off, 64);
    int lane = threadIdx.x & 63, w = threadIdx.x >> 6;
    __syncthreads();
    if (lane == 0) red[w] = v;
    __syncthreads();
    return red[0] + red[1] + red[2] + red[3];
}

// ---------------- transpose + f32->bf16 convert (32x32 tiles) ---------------
__global__ __launch_bounds__(256) void tcvt_k(const float* __restrict__ in,
                                              bf16* __restrict__ out, int R, int C) {
    __shared__ float t[32][33];
    size_t hoff = (size_t)blockIdx.z * R * C;
    int c0 = blockIdx.x * 32, r0 = blockIdx.y * 32;
    int x = threadIdx.x & 31, y = threadIdx.x >> 5;
#pragma unroll
    for (int p = 0; p < 4; ++p)
        t[y + 8 * p][x] = in[hoff + (size_t)(r0 + y + 8 * p) * C + c0 + x];
    __syncthreads();
#pragma unroll
    for (int p = 0; p < 4; ++p)
        out[hoff + (size_t)(c0 + y + 8 * p) * R + r0 + x] = (bf16)t[x][y + 8 * p];
}

// ---------------- RoPE cos/sin HALF tables (pairs share angle) --------------
__global__ __launch_bounds__(256) void rope_tab_k(bf16* __restrict__ cosH,
                                                  bf16* __restrict__ sinH) {
    int k = blockIdx.x * 256 + threadIdx.x;     // 0..NN/2-1
    int t = blockIdx.y;
    float q = (float)(2 * k);
    float f = exp2f(q * (-16.0f / (float)NN)) * 0.15915494309189535f;
    float u = fmodf((float)t * f, 1.0f);
    float a = u * 6.283185307179586f;
    cosH[(size_t)t * (NN / 2) + k] = (bf16)cosf(a);
    sinH[(size_t)t * (NN / 2) + k] = (bf16)sinf(a);
}

// ---------------- x = LN(embed[idx]) (writes f32 + bf16 + bf16^T) -----------
__global__ __launch_bounds__(256) void embed_ln_k(const int* __restrict__ idx,
                                                  const float* __restrict__ embed,
                                                  float* __restrict__ x,
                                                  bf16* __restrict__ xb,
                                                  bf16* __restrict__ xbT) {
    __shared__ float red[4];
    int t = blockIdx.x, d = threadIdx.x;
    float e = embed[(size_t)idx[t] * D + d];
    float m = blk_sum256(e, red) * (1.0f / D);
    float df = e - m;
    float vv = blk_sum256(df * df, red) * (1.0f / D);
    float r = df * rsqrtf(vv + EPSF);
    x[(size_t)t * D + d] = r;
    xb[(size_t)t * D + d] = (bf16)r;
    xbT[(size_t)d * T + t] = (bf16)r;
}

// ---------------- MFMA 64x64 core v2: BK=64, 2-phase gload_lds pipeline -----
// (R7-proven, verbatim) A row-major [m][k] (lda), B as rows of B^T [n][k].
__device__ __forceinline__ void gemm_core64(const bf16* __restrict__ Ap, size_t lda,
                                            const bf16* __restrict__ Bp, size_t ldb,
                                            int ksteps, bf16* lds,
                                            f32x4 acc[2][2], int tid) {
    int lane = tid & 63, wid = tid >> 6;
    int wr = (wid >> 1) * 32, wc = (wid & 1) * 32;
    int fr = lane & 15, s = lane >> 4;
    int srow = wid * 16 + (lane >> 3);
    int sx   = ((lane & 7) ^ (srow & 7)) * 8;      // inverse-swizzled src elem
    const bf16* ag = Ap + (size_t)srow * lda + sx;
    const bf16* bg = Bp + (size_t)srow * ldb + sx;
    bf16* a_w = lds + wid * 1024;                  // wave-uniform dests
    bf16* b_w = lds + 8192 + wid * 1024;
    int ar = wr + fr, br = wc + fr;
    int aoff0 = ar * 128 + (((s)     ^ (ar & 7)) << 4);
    int aoff1 = ar * 128 + (((4 + s) ^ (ar & 7)) << 4);
    int boff0 = br * 128 + (((s)     ^ (br & 7)) << 4);
    int boff1 = br * 128 + (((4 + s) ^ (br & 7)) << 4);
    GLD16(ag, a_w);  GLD16(ag + 8 * lda, a_w + 512);
    GLD16(bg, b_w);  GLD16(bg + 8 * ldb, b_w + 512);
    __syncthreads();
    for (int ks = 0; ks < ksteps; ++ks) {
        int cur = ks & 1;
        if (ks + 1 < ksteps) {                     // issue-early: overlap w/ MFMA
            int nxt = cur ^ 1;
            size_t ko = (size_t)(ks + 1) * 64;
            bf16* an = lds + nxt * 4096 + wid * 1024;
            bf16* bn = lds + 8192 + nxt * 4096 + wid * 1024;
            GLD16(ag + ko, an);  GLD16(ag + ko + 8 * lda, an + 512);
            GLD16(bg + ko, bn);  GLD16(bg + ko + 8 * ldb, bn + 512);
        }
        const char* cA = (const char*)(lds + cur * 4096);
        const char* cB = (const char*)(lds + 8192 + cur * 4096);
        bf16x8 a00 = *(const bf16x8*)(cA + aoff0);
        bf16x8 a01 = *(const bf16x8*)(cA + aoff1);
        bf16x8 a10 = *(const bf16x8*)(cA + aoff0 + 2048);  // row +16
        bf16x8 a11 = *(const bf16x8*)(cA + aoff1 + 2048);
        bf16x8 b00 = *(const bf16x8*)(cB + boff0);
        bf16x8 b01 = *(const bf16x8*)(cB + boff1);
        bf16x8 b10 = *(const bf16x8*)(cB + boff0 + 2048);
        bf16x8 b11 = *(const bf16x8*)(cB + boff1 + 2048);
        acc[0][0] = MFMA16(a00, b00, acc[0][0]);
        acc[0][0] = MFMA16(a01, b01, acc[0][0]);
        acc[0][1] = MFMA16(a00, b10, acc[0][1]);
        acc[0][1] = MFMA16(a01, b11, acc[0][1]);
        acc[1][0] = MFMA16(a10, b00, acc[1][0]);
        acc[1][0] = MFMA16(a11, b01, acc[1][0]);
        acc[1][1] = MFMA16(a10, b10, acc[1][1]);
        acc[1][1] = MFMA16(a11, b11, acc[1][1]);
        __syncthreads();   // drains next-tile vmcnt + WAR on cur buffer
    }
}

// ======== 128x128 MFMA core v2 — core64 algebra extended to 128 rows ========
// (R13-proven) BK=64, 4 waves (2x2 of 64x64), same swizzle (key = fr&7).
// LDS: A[2][128][64] bf16 (32KB) at 0, B same at elem 16384. Total 64KB.
__device__ __forceinline__ void gemm_core128v2(const bf16* __restrict__ Ap, size_t lda,
                                               const bf16* __restrict__ Bp, size_t ldb,
                                               int ksteps, bf16* lds,
                                               f32x4 acc[4][4], int tid) {
    int lane = tid & 63, wid = tid >> 6;
    int wr = (wid >> 1) * 64, wc = (wid & 1) * 64;
    int fr = lane & 15, s = lane >> 4;
    int srow = wid * 16 + (lane >> 3);             // rows 16w..16w+7 (+8, +64, +72)
    int sx   = ((lane & 7) ^ (srow & 7)) * 8;      // inverse-swizzled src elem
    const bf16* ag = Ap + (size_t)srow * lda + sx; // (srow+64)&7 == srow&7: same sx
    const bf16* bg = Bp + (size_t)srow * ldb + sx;
    bf16* a_w = lds + wid * 1024;                  // wave-uniform dests (elems)
    bf16* b_w = lds + 16384 + wid * 1024;
    int ar = wr + fr, br = wc + fr;                // (ar&7) == (fr&7)
    int aoff0 = (ar & 63) * 128 + (((s)     ^ (fr & 7)) << 4) + (wr >> 6) * 8192;
    int aoff1 = (ar & 63) * 128 + (((4 + s) ^ (fr & 7)) << 4) + (wr >> 6) * 8192;
    int boff0 = (br & 63) * 128 + (((s)     ^ (fr & 7)) << 4) + (wc >> 6) * 8192;
    int boff1 = (br & 63) * 128 + (((4 + s) ^ (fr & 7)) << 4) + (wc >> 6) * 8192;
    // prologue: stage kstep 0 into buffer 0
    GLD16(ag, a_w);                 GLD16(ag + 8 * lda, a_w + 512);
    GLD16(ag + 64 * lda, a_w + 4096); GLD16(ag + 72 * lda, a_w + 4608);
    GLD16(bg, b_w);                 GLD16(bg + 8 * ldb, b_w + 512);
    GLD16(bg + 64 * ldb, b_w + 4096); GLD16(bg + 72 * ldb, b_w + 4608);
    __syncthreads();
    for (int ks = 0; ks < ksteps; ++ks) {
        int cur = ks & 1;
        if (ks + 1 < ksteps) {                     // issue-early: overlap w/ MFMA
            int nxt = cur ^ 1;
            size_t ko = (size_t)(ks + 1) * 64;
            bf16* an = lds + nxt * 8192 + wid * 1024;
            bf16* bn = lds + 16384 + nxt * 8192 + wid * 1024;
            GLD16(ag + ko, an);                 GLD16(ag + ko + 8 * lda, an + 512);
            GLD16(ag + ko + 64 * lda, an + 4096); GLD16(ag + ko + 72 * lda, an + 4608);
            GLD16(bg + ko, bn);                 GLD16(bg + ko + 8 * ldb, bn + 512);
            GLD16(bg + ko + 64 * ldb, bn + 4096); GLD16(bg + ko + 72 * ldb, bn + 4608);
        }
        const char* cA = (const char*)(lds + cur * 8192);
        const char* cB = (const char*)(lds + 16384 + cur * 8192);
        bf16x8 a0[4], a1[4], b0[4], b1[4];
#pragma unroll
        for (int i = 0; i < 4; ++i) {
            a0[i] = *(const bf16x8*)(cA + aoff0 + i * 2048);   // row +16 each
            a1[i] = *(const bf16x8*)(cA + aoff1 + i * 2048);
            b0[i] = *(const bf16x8*)(cB + boff0 + i * 2048);
            b1[i] = *(const bf16x8*)(cB + boff1 + i * 2048);
        }
#pragma unroll
        for (int i = 0; i < 4; ++i)
#pragma unroll
            for (int j = 0; j < 4; ++j) {
                acc[i][j] = MFMA16(a0[i], b0[j], acc[i][j]);
                acc[i][j] = MFMA16(a1[i], b1[j], acc[i][j]);
            }
        __syncthreads();   // drains next-tile vmcnt + WAR on cur buffer
    }
}

// ---------------- encoder GEMM + relu (+RoPE / *old), 128² + coalesced ------
// MODE 0: xs=relu(C), qr=rope(xs). MODE 1: xs*=relu(C). Full-tile LDS staging.
template <int MODE>
__global__ __launch_bounds__(256) void enc_mfma_k(const bf16* __restrict__ A,
                                                  const bf16* __restrict__ Wt,
                                                  bf16* __restrict__ xs,
                                                  bf16* __restrict__ qr,
                                                  const bf16* __restrict__ cosH,
                                                  const bf16* __restrict__ sinH,
                                                  int aHeadStride) {
    __shared__ __align__(16) bf16 smem[32768];     // 64 KB (core), reused as Ot
    bf16 (*Ot)[136] = (bf16(*)[136])smem;          // 128x136 bf16 = 34,816 B
    int h = blockIdx.z;
    int row0 = blockIdx.y * 128, col0 = blockIdx.x * 128;
    const bf16* Ap = A + (size_t)h * aHeadStride + (size_t)row0 * D;
    const bf16* Bp = Wt + ((size_t)h * NN + col0) * D;
    int tid = threadIdx.x;
    f32x4 acc[4][4];
#pragma unroll
    for (int i = 0; i < 4; ++i)
#pragma unroll
        for (int j = 0; j < 4; ++j) acc[i][j] = f32x4{0.f, 0.f, 0.f, 0.f};
    gemm_core128v2(Ap, D, Bp, D, D / 64, smem, acc, tid);
    // core ends with __syncthreads(): LDS free for reuse

    int lane = tid & 63, wid = tid >> 6;
    int wr = (wid >> 1) * 64, wc = (wid & 1) * 64;
    int fr = lane & 15, fq = lane >> 4;
    // ---- stage relu tile ----
#pragma unroll
    for (int mi = 0; mi < 4; ++mi)
#pragma unroll
        for (int ni = 0; ni < 4; ++ni)
#pragma unroll
            for (int j = 0; j < 4; ++j)
                Ot[wr + mi * 16 + fq * 4 + j][wc + ni * 16 + fr] =
                    (bf16)fmaxf((float)acc[mi][ni][j], 0.0f);
    __syncthreads();
    int rrow = tid >> 4;             // 0..15
    int cb = (tid & 15) * 8;         // elem col (16B chunks)
    if (MODE == 0) {
        // coalesced xs stores: 8 passes x 16B/lane
#pragma unroll
        for (int p = 0; p < 8; ++p) {
            int row = p * 16 + rrow;
            *(bf16x8*)(xs + ((size_t)h * T + row0 + row) * NN + col0 + cb) =
                *(const bf16x8*)&Ot[row][cb];
        }
        __syncthreads();
        // ---- stage rope tile (reuse Ot) ----
#pragma unroll
        for (int mi = 0; mi < 4; ++mi)
#pragma unroll
            for (int ni = 0; ni < 4; ++ni)
#pragma unroll
                for (int j = 0; j < 4; ++j) {
                    float v = fmaxf((float)acc[mi][ni][j], 0.0f);
                    float pv = __shfl_xor(v, 1, 64);       // partner col n^1
                    int m = row0 + wr + mi * 16 + fq * 4 + j;
                    int n = col0 + wc + ni * 16 + fr;
                    float cs = (float)cosH[(size_t)m * (NN / 2) + (n >> 1)];
                    float sn = (float)sinH[(size_t)m * (NN / 2) + (n >> 1)];
                    Ot[wr + mi * 16 + fq * 4 + j][wc + ni * 16 + fr] =
                        (bf16)(v * cs + ((n & 1) ? pv * sn : -pv * sn));
                }
        __syncthreads();
#pragma unroll
        for (int p = 0; p < 8; ++p) {
            int row = p * 16 + rrow;
            *(bf16x8*)(qr + ((size_t)h * T + row0 + row) * NN + col0 + cb) =
                *(const bf16x8*)&Ot[row][cb];
        }
    } else {
        // coalesced read-modify-write of xs
#pragma unroll
        for (int p = 0; p < 8; ++p) {
            int row = p * 16 + rrow;
            size_t gb = ((size_t)h * T + row0 + row) * NN + col0 + cb;
            bf16x8 o = *(const bf16x8*)&Ot[row][cb];
            bf16x8 xv = *(const bf16x8*)(xs + gb);
            bf16x8 r;
#pragma unroll
            for (int k = 0; k < 8; ++k)
                r[k] = (bf16)((float)o[k] * (float)xv[k]);
            *(bf16x8*)(xs + gb) = r;
        }
    }
}

// ---------------- scores GEMM: spartb[ks][h][t][s] bf16 (lower-tri tiles) ---
// (R13-proven) 1-D grid, 576 blocks: bid%16 = (h,ksplit) group
__global__ __launch_bounds__(256) void qq_mfma_k(const bf16* __restrict__ qrb,
                                                 bf16* __restrict__ spartb) {
    __shared__ __align__(16) char smem[32768];
    int g = blockIdx.x & 15;          // (h, ksplit) group
    int h = g >> 2, ksplit = g & 3;
    int p = blockIdx.x >> 4;          // 0..35 -> (ti,tj), tj<=ti
    int ti = 0, accu = 0;
    while (accu + ti + 1 <= p) { ++ti; accu += ti; }
    int tj = p - accu;
    const bf16* Q = qrb + (size_t)h * T * NN + (size_t)ksplit * (NN / QKS);
    const bf16* Ap = Q + (size_t)(ti * 64) * NN;
    const bf16* Bp = Q + (size_t)(tj * 64) * NN;
    int tid = threadIdx.x;
    f32x4 acc[2][2];
#pragma unroll
    for (int i = 0; i < 2; ++i)
#pragma unroll
        for (int j = 0; j < 2; ++j) acc[i][j] = f32x4{0.f, 0.f, 0.f, 0.f};
    gemm_core64(Ap, NN, Bp, NN, (NN / QKS) / 64, (bf16*)smem, acc, tid);

    int lane = tid & 63, wid = tid >> 6;
    int wr = (wid >> 1) * 32, wc = (wid & 1) * 32;
    int fr = lane & 15, fq = lane >> 4;
    bf16* outp = spartb + (size_t)(ksplit * H + h) * T * T;
#pragma unroll
    for (int mi = 0; mi < 2; ++mi)
#pragma unroll
        for (int ni = 0; ni < 2; ++ni) {
            int s = tj * 64 + wc + ni * 16 + fr;
            int mbase = ti * 64 + wr + mi * 16 + fq * 4;
#pragma unroll
            for (int j = 0; j < 4; ++j)
                outp[(size_t)(mbase + j) * T + s] = (bf16)acc[mi][ni][j];
        }
}

// ---------------- sb[h][t][s] = bf16(sum_ks spartb), strict causal mask -----
__global__ __launch_bounds__(256) void mask_cvt_k(const bf16* __restrict__ spartb,
                                                  bf16* __restrict__ sb) {
    int t = blockIdx.x * 2 + (threadIdx.x >> 7);
    int h = blockIdx.y;
    int l = threadIdx.x & 127;
    int s = l * 4;
    const bf16* s0 = spartb + ((size_t)h * T + t) * T + s;
    const size_t st = (size_t)H * T * T;
    float a0 = 0, a1 = 0, a2 = 0, a3 = 0;
#pragma unroll
    for (int k = 0; k < QKS; ++k) {
        bf16x4 w = *(const bf16x4*)(s0 + k * st);
        a0 += (float)w[0]; a1 += (float)w[1]; a2 += (float)w[2]; a3 += (float)w[3];
    }
    bf16x4 o;
    o[0] = (bf16)((s + 0 < t) ? a0 : 0.0f);
    o[1] = (bf16)((s + 1 < t) ? a1 : 0.0f);
    o[2] = (bf16)((s + 2 < t) ? a2 : 0.0f);
    o[3] = (bf16)((s + 3 < t) ? a3 : 0.0f);
    *(bf16x4*)(sb + ((size_t)h * T + t) * T + s) = o;
}

// ---------------- av: ykv_pre[h][t][d] = sum_s sb[t,s] * x[s,d] (MFMA) ------
__global__ __launch_bounds__(256) void av_mfma_k(const bf16* __restrict__ sb,
                                                 const bf16* __restrict__ xbT,
                                                 float* __restrict__ ykv_pre) {
    __shared__ __align__(16) char smem[32768];
    int h = blockIdx.z;
    int ti = blockIdx.y;
    int row0 = ti * 64, col0 = blockIdx.x * 64;
    const bf16* Ap = sb + ((size_t)h * T + row0) * T;
    const bf16* Bp = xbT + (size_t)col0 * T;
    int tid = threadIdx.x;
    f32x4 acc[2][2];
#pragma unroll
    for (int i = 0; i < 2; ++i)
#pragma unroll
        for (int j = 0; j < 2; ++j) acc[i][j] = f32x4{0.f, 0.f, 0.f, 0.f};
    // causal: sb[t][s]==0 for s>=t, so only need k < (ti+1)*64
    gemm_core64(Ap, T, Bp, T, ti + 1, (bf16*)smem, acc, tid);

    int lane = tid & 63, wid = tid >> 6;
    int wr = (wid >> 1) * 32, wc = (wid & 1) * 32;
    int fr = lane & 15, fq = lane >> 4;
#pragma unroll
    for (int mi = 0; mi < 2; ++mi)
#pragma unroll
        for (int ni = 0; ni < 2; ++ni) {
            int n = col0 + wc + ni * 16 + fr;
            int mbase = row0 + wr + mi * 16 + fq * 4;
#pragma unroll
            for (int j = 0; j < 4; ++j)
                ykv_pre[((size_t)h * T + (mbase + j)) * D + n] = acc[mi][ni][j];
        }
}

// ---------------- ykv LN: ykvb = LN(ykv_pre) --------------------------------
__global__ __launch_bounds__(256) void ykv_ln_k(const float* __restrict__ ykv_pre,
                                                bf16* __restrict__ ykvb) {
    __shared__ float red[4];
    int t = blockIdx.x, h = blockIdx.y, d = threadIdx.x;
    float a = ykv_pre[((size_t)h * T + t) * D + d];
    float m = blk_sum256(a, red) * (1.0f / D);
    float df = a - m;
    float vv = blk_sum256(df * df, red) * (1.0f / D);
    ykvb[((size_t)h * T + t) * D + d] = (bf16)(df * rsqrtf(vv + EPSF));
}

// ---------------- decoder GEMM (split-K=16, 64x64 tiles) --------------------
// (R13-proven) 1-D grid, 512 blocks: ks = bid%16
__global__ __launch_bounds__(256) void dec_mfma_k(const bf16* __restrict__ xyb,
                                                  const bf16* __restrict__ decT,
                                                  float* __restrict__ ypart) {
    __shared__ __align__(16) char smem[32768];
    int ks = blockIdx.x & 15;
    int t  = blockIdx.x >> 4;          // 0..31: col = t&3, row = t>>2
    int col0 = (t & 3) * 64, row0 = (t >> 2) * 64;
    int cbeg = ks * ((H * NN) / DSPLIT);   // 2048-wide slices, within one head
    int h = cbeg >> 13, n0 = cbeg & (NN - 1);
    const bf16* Ap = xyb + ((size_t)h * T + row0) * NN + n0;
    const bf16* Bp = decT + (size_t)col0 * (H * NN) + cbeg;
    int tid = threadIdx.x;
    f32x4 acc[2][2];
#pragma unroll
    for (int i = 0; i < 2; ++i)
#pragma unroll
        for (int j = 0; j < 2; ++j) acc[i][j] = f32x4{0.f, 0.f, 0.f, 0.f};
    gemm_core64(Ap, NN, Bp, H * NN, (H * NN / DSPLIT) / 64, (bf16*)smem, acc, tid);

    int lane = tid & 63, wid = tid >> 6;
    int wr = (wid >> 1) * 32, wc = (wid & 1) * 32;
    int fr = lane & 15, fq = lane >> 4;
#pragma unroll
    for (int mi = 0; mi < 2; ++mi)
#pragma unroll
        for (int ni = 0; ni < 2; ++ni) {
            int n = col0 + wc + ni * 16 + fr;
            int mbase = row0 + wr + mi * 16 + fq * 4;
#pragma unroll
            for (int j = 0; j < 4; ++j)
                ypart[((size_t)ks * T + (mbase + j)) * D + n] = acc[mi][ni][j];
        }
}

// ---------------- y = LN(sum ypart); x = LN(x + y); bf16 + bf16^T copies ----
__global__ __launch_bounds__(256) void final_ln_k(const float* __restrict__ ypart,
                                                  float* __restrict__ x,
                                                  bf16* __restrict__ xb,
                                                  bf16* __restrict__ xbT) {
    __shared__ float red[4];
    int t = blockIdx.x, d = threadIdx.x;
    float ys = 0.0f;
#pragma unroll
    for (int ks = 0; ks < DSPLIT; ++ks) ys += ypart[((size_t)ks * T + t) * D + d];
    float m = blk_sum256(ys, red) * (1.0f / D);
    float df = ys - m;
    float vv = blk_sum256(df * df, red) * (1.0f / D);
    float yln = df * rsqrtf(vv + EPSF);
    float val = x[(size_t)t * D + d] + yln;
    float m2 = blk_sum256(val, red) * (1.0f / D);
    float df2 = val - m2;
    float v2 = blk_sum256(df2 * df2, red) * (1.0f / D);
    float r = df2 * rsqrtf(v2 + EPSF);
    x[(size_t)t * D + d] = r;
    xb[(size_t)t * D + d] = (bf16)r;
    xbT[(size_t)d * T + t] = (bf16)r;
}

// ---------------- logits = x @ lm_head (f32) --------------------------------
__global__ __launch_bounds__(256) void logits_k(const float* __restrict__ x,
                                                const float* __restrict__ lm,
                                                float* __restrict__ out) {
    int t = blockIdx.x, v = threadIdx.x;
    float a = 0.0f;
    for (int d = 0; d < D; ++d)
        a = fmaf(x[(size_t)t * D + d], lm[(size_t)d * V + v], a);
    out[(size_t)t * V + v] = a;
}

extern "C" void kernel_launch(void* const* d_in, const int* in_sizes, int n_in,
                              void* d_out, int out_size, void* d_ws, size_t ws_size,
                              hipStream_t stream) {
    const int*   idx       = (const int*)d_in[0];
    const float* embed     = (const float*)d_in[1];
    const float* encoder   = (const float*)d_in[2];
    const float* encoder_v = (const float*)d_in[3];
    const float* decoder   = (const float*)d_in[4];
    const float* lm_head   = (const float*)d_in[5];
    float* out = (float*)d_out;

    // ---- workspace layout (146.8 MB — identical to passing R13) ----
    char* W = (char*)d_ws;
    float* x       = (float*)W; W += (size_t)T * D * 4;
    float* scratch = (float*)W; W += (size_t)QKS * H * T * T * 4;  // spartb / ykv_pre / ypart union
    bf16* xb    = (bf16*)W; W += (size_t)T * D * 2;
    bf16* xbT   = (bf16*)W; W += (size_t)D * T * 2;
    bf16* sb    = (bf16*)W; W += (size_t)H * T * T * 2;
    bf16* ykvb  = (bf16*)W; W += (size_t)H * T * D * 2;
    bf16* encT  = (bf16*)W; W += (size_t)H * NN * D * 2;
    bf16* encVT = (bf16*)W; W += (size_t)H * NN * D * 2;
    bf16* decT  = (bf16*)W; W += (size_t)D * H * NN * 2;
    bf16* cosH  = (bf16*)W; W += (size_t)T * (NN / 2) * 2;
    bf16* sinH  = (bf16*)W; W += (size_t)T * (NN / 2) * 2;
    bf16* xs    = (bf16*)W; W += (size_t)H * T * NN * 2;
    bf16* qr    = (bf16*)W; W += (size_t)H * T * NN * 2;
    bf16* spartb = (bf16*)scratch;   // bf16 alias of the scratch union

    // ---- one-time per launch: weight transpose+convert, RoPE tables ----
    tcvt_k<<<dim3(NN / 32, D / 32, H), 256, 0, stream>>>(encoder, encT, D, NN);
    tcvt_k<<<dim3(NN / 32, D / 32, H), 256, 0, stream>>>(encoder_v, encVT, D, NN);
    tcvt_k<<<dim3(D / 32, (H * NN) / 32, 1), 256, 0, stream>>>(decoder, decT, H * NN, D);
    rope_tab_k<<<dim3((NN / 2) / 256, T), 256, 0, stream>>>(cosH, sinH);

    embed_ln_k<<<T, 256, 0, stream>>>(idx, embed, x, xb, xbT);

    for (int layer = 0; layer < N_LAYER; ++layer) {
        enc_mfma_k<0><<<dim3(NN / 128, T / 128, H), 256, 0, stream>>>(
            xb, encT, xs, qr, cosH, sinH, 0);
        qq_mfma_k<<<576, 256, 0, stream>>>(qr, spartb);
        mask_cvt_k<<<dim3(T / 2, H), 256, 0, stream>>>(spartb, sb);
        av_mfma_k<<<dim3(D / 64, T / 64, H), 256, 0, stream>>>(sb, xbT, scratch);
        ykv_ln_k<<<dim3(T, H), 256, 0, stream>>>(scratch, ykvb);
        enc_mfma_k<1><<<dim3(NN / 128, T / 128, H), 256, 0, stream>>>(
            ykvb, encVT, xs, nullptr, nullptr, nullptr, T * D);
        dec_mfma_k<<<512, 256, 0, stream>>>(xs, decT, scratch);
        final_ln_k<<<T, 256, 0, stream>>>(scratch, x, xb, xbT);
    }

    logits_k<<<T, 256, 0, stream>>>(x, lm_head, out);
}

// Round 16
// 638.268 us; speedup vs baseline: 1.0443x; 1.0075x over previous
//
#include <hip/hip_runtime.h>
#include <hip/hip_bf16.h>

#define T   512
#define D   256
#define H   4
#define NN  8192
#define V   256
#define EPSF 1e-5f
#define QKS 4          // split-K for scores GEMM
#define DSPLIT 16      // split-K for decoder GEMM
#define N_LAYER 6

typedef __bf16 bf16;
typedef __attribute__((__ext_vector_type__(8))) __bf16 bf16x8;
typedef __attribute__((__ext_vector_type__(4))) __bf16 bf16x4;
typedef __attribute__((__ext_vector_type__(4))) float  f32x4;

#define MFMA16(a, b, c) __builtin_amdgcn_mfma_f32_16x16x32_bf16((a), (b), (c), 0, 0, 0)
// async global->LDS, 16B per lane; LDS dest is wave-uniform base + lane*16
#define GLD16(g, l)                                                         \
    __builtin_amdgcn_global_load_lds(                                       \
        (const __attribute__((address_space(1))) void*)(g),                 \
        (__attribute__((address_space(3))) void*)(l), 16, 0, 0)

// ---------------- block-wide sum over 256 threads ---------------------------
__device__ __forceinline__ float blk_sum256(float v, float* red) {
#pragma unroll
    for (int off = 32; off > 0; off >>= 1) v += __shfl_down(v, off, 64);
    int lane = threadIdx.x & 63, w = threadIdx.x >> 6;
    __syncthreads();
    if (lane == 0) red[w] = v;
    __syncthreads();
    return red[0] + red[1] + red[2] + red[3];
}

// ---------------- transpose + f32->bf16 convert (32x32 tiles) ---------------
__global__ __launch_bounds__(256) void tcvt_k(const float* __restrict__ in,
                                              bf16* __restrict__ out, int R, int C) {
    __shared__ float t[32][33];
    size_t hoff = (size_t)blockIdx.z * R * C;
    int c0 = blockIdx.x * 32, r0 = blockIdx.y * 32;
    int x = threadIdx.x & 31, y = threadIdx.x >> 5;
#pragma unroll
    for (int p = 0; p < 4; ++p)
        t[y + 8 * p][x] = in[hoff + (size_t)(r0 + y + 8 * p) * C + c0 + x];
    __syncthreads();
#pragma unroll
    for (int p = 0; p < 4; ++p)
        out[hoff + (size_t)(c0 + y + 8 * p) * R + r0 + x] = (bf16)t[x][y + 8 * p];
}

// ---------------- RoPE cos/sin HALF tables (pairs share angle) --------------
// v_sin/cos take REVOLUTIONS: u in [0,1) feeds the HW unit directly.
__global__ __launch_bounds__(256) void rope_tab_k(bf16* __restrict__ cosH,
                                                  bf16* __restrict__ sinH) {
    int k = blockIdx.x * 256 + threadIdx.x;     // 0..NN/2-1
    int t = blockIdx.y;
    float q = (float)(2 * k);
    float f = exp2f(q * (-16.0f / (float)NN)) * 0.15915494309189535f;
    float u = fmodf((float)t * f, 1.0f);        // angle in revolutions
    cosH[(size_t)t * (NN / 2) + k] = (bf16)__builtin_amdgcn_cosf(u);
    sinH[(size_t)t * (NN / 2) + k] = (bf16)__builtin_amdgcn_sinf(u);
}

// ---------------- x = LN(embed[idx]) (writes f32 + bf16 + bf16^T) -----------
__global__ __launch_bounds__(256) void embed_ln_k(const int* __restrict__ idx,
                                                  const float* __restrict__ embed,
                                                  float* __restrict__ x,
                                                  bf16* __restrict__ xb,
                                                  bf16* __restrict__ xbT) {
    __shared__ float red[4];
    int t = blockIdx.x, d = threadIdx.x;
    float e = embed[(size_t)idx[t] * D + d];
    float m = blk_sum256(e, red) * (1.0f / D);
    float df = e - m;
    float vv = blk_sum256(df * df, red) * (1.0f / D);
    float r = df * rsqrtf(vv + EPSF);
    x[(size_t)t * D + d] = r;
    xb[(size_t)t * D + d] = (bf16)r;
    xbT[(size_t)d * T + t] = (bf16)r;
}

// ---------------- MFMA 64x64 core v2: BK=64, 2-phase gload_lds pipeline -----
// (R7-proven, verbatim) A row-major [m][k] (lda), B as rows of B^T [n][k].
__device__ __forceinline__ void gemm_core64(const bf16* __restrict__ Ap, size_t lda,
                                            const bf16* __restrict__ Bp, size_t ldb,
                                            int ksteps, bf16* lds,
                                            f32x4 acc[2][2], int tid) {
    int lane = tid & 63, wid = tid >> 6;
    int wr = (wid >> 1) * 32, wc = (wid & 1) * 32;
    int fr = lane & 15, s = lane >> 4;
    int srow = wid * 16 + (lane >> 3);
    int sx   = ((lane & 7) ^ (srow & 7)) * 8;      // inverse-swizzled src elem
    const bf16* ag = Ap + (size_t)srow * lda + sx;
    const bf16* bg = Bp + (size_t)srow * ldb + sx;
    bf16* a_w = lds + wid * 1024;                  // wave-uniform dests
    bf16* b_w = lds + 8192 + wid * 1024;
    int ar = wr + fr, br = wc + fr;
    int aoff0 = ar * 128 + (((s)     ^ (ar & 7)) << 4);
    int aoff1 = ar * 128 + (((4 + s) ^ (ar & 7)) << 4);
    int boff0 = br * 128 + (((s)     ^ (br & 7)) << 4);
    int boff1 = br * 128 + (((4 + s) ^ (br & 7)) << 4);
    GLD16(ag, a_w);  GLD16(ag + 8 * lda, a_w + 512);
    GLD16(bg, b_w);  GLD16(bg + 8 * ldb, b_w + 512);
    __syncthreads();
    for (int ks = 0; ks < ksteps; ++ks) {
        int cur = ks & 1;
        if (ks + 1 < ksteps) {                     // issue-early: overlap w/ MFMA
            int nxt = cur ^ 1;
            size_t ko = (size_t)(ks + 1) * 64;
            bf16* an = lds + nxt * 4096 + wid * 1024;
            bf16* bn = lds + 8192 + nxt * 4096 + wid * 1024;
            GLD16(ag + ko, an);  GLD16(ag + ko + 8 * lda, an + 512);
            GLD16(bg + ko, bn);  GLD16(bg + ko + 8 * ldb, bn + 512);
        }
        const char* cA = (const char*)(lds + cur * 4096);
        const char* cB = (const char*)(lds + 8192 + cur * 4096);
        bf16x8 a00 = *(const bf16x8*)(cA + aoff0);
        bf16x8 a01 = *(const bf16x8*)(cA + aoff1);
        bf16x8 a10 = *(const bf16x8*)(cA + aoff0 + 2048);  // row +16
        bf16x8 a11 = *(const bf16x8*)(cA + aoff1 + 2048);
        bf16x8 b00 = *(const bf16x8*)(cB + boff0);
        bf16x8 b01 = *(const bf16x8*)(cB + boff1);
        bf16x8 b10 = *(const bf16x8*)(cB + boff0 + 2048);
        bf16x8 b11 = *(const bf16x8*)(cB + boff1 + 2048);
        acc[0][0] = MFMA16(a00, b00, acc[0][0]);
        acc[0][0] = MFMA16(a01, b01, acc[0][0]);
        acc[0][1] = MFMA16(a00, b10, acc[0][1]);
        acc[0][1] = MFMA16(a01, b11, acc[0][1]);
        acc[1][0] = MFMA16(a10, b00, acc[1][0]);
        acc[1][0] = MFMA16(a11, b01, acc[1][0]);
        acc[1][1] = MFMA16(a10, b10, acc[1][1]);
        acc[1][1] = MFMA16(a11, b11, acc[1][1]);
        __syncthreads();   // drains next-tile vmcnt + WAR on cur buffer
    }
}

// ======== 128x128 MFMA core v2 — core64 algebra extended to 128 rows ========
// (R13-proven) BK=64, 4 waves (2x2 of 64x64), same swizzle (key = fr&7).
// LDS: A[2][128][64] bf16 (32KB) at 0, B same at elem 16384. Total 64KB.
__device__ __forceinline__ void gemm_core128v2(const bf16* __restrict__ Ap, size_t lda,
                                               const bf16* __restrict__ Bp, size_t ldb,
                                               int ksteps, bf16* lds,
                                               f32x4 acc[4][4], int tid) {
    int lane = tid & 63, wid = tid >> 6;
    int wr = (wid >> 1) * 64, wc = (wid & 1) * 64;
    int fr = lane & 15, s = lane >> 4;
    int srow = wid * 16 + (lane >> 3);             // rows 16w..16w+7 (+8, +64, +72)
    int sx   = ((lane & 7) ^ (srow & 7)) * 8;      // inverse-swizzled src elem
    const bf16* ag = Ap + (size_t)srow * lda + sx; // (srow+64)&7 == srow&7: same sx
    const bf16* bg = Bp + (size_t)srow * ldb + sx;
    bf16* a_w = lds + wid * 1024;                  // wave-uniform dests (elems)
    bf16* b_w = lds + 16384 + wid * 1024;
    int ar = wr + fr, br = wc + fr;                // (ar&7) == (fr&7)
    int aoff0 = (ar & 63) * 128 + (((s)     ^ (fr & 7)) << 4) + (wr >> 6) * 8192;
    int aoff1 = (ar & 63) * 128 + (((4 + s) ^ (fr & 7)) << 4) + (wr >> 6) * 8192;
    int boff0 = (br & 63) * 128 + (((s)     ^ (fr & 7)) << 4) + (wc >> 6) * 8192;
    int boff1 = (br & 63) * 128 + (((4 + s) ^ (fr & 7)) << 4) + (wc >> 6) * 8192;
    // prologue: stage kstep 0 into buffer 0
    GLD16(ag, a_w);                 GLD16(ag + 8 * lda, a_w + 512);
    GLD16(ag + 64 * lda, a_w + 4096); GLD16(ag + 72 * lda, a_w + 4608);
    GLD16(bg, b_w);                 GLD16(bg + 8 * ldb, b_w + 512);
    GLD16(bg + 64 * ldb, b_w + 4096); GLD16(bg + 72 * ldb, b_w + 4608);
    __syncthreads();
    for (int ks = 0; ks < ksteps; ++ks) {
        int cur = ks & 1;
        if (ks + 1 < ksteps) {                     // issue-early: overlap w/ MFMA
            int nxt = cur ^ 1;
            size_t ko = (size_t)(ks + 1) * 64;
            bf16* an = lds + nxt * 8192 + wid * 1024;
            bf16* bn = lds + 16384 + nxt * 8192 + wid * 1024;
            GLD16(ag + ko, an);                 GLD16(ag + ko + 8 * lda, an + 512);
            GLD16(ag + ko + 64 * lda, an + 4096); GLD16(ag + ko + 72 * lda, an + 4608);
            GLD16(bg + ko, bn);                 GLD16(bg + ko + 8 * ldb, bn + 512);
            GLD16(bg + ko + 64 * ldb, bn + 4096); GLD16(bg + ko + 72 * ldb, bn + 4608);
        }
        const char* cA = (const char*)(lds + cur * 8192);
        const char* cB = (const char*)(lds + 16384 + cur * 8192);
        bf16x8 a0[4], a1[4], b0[4], b1[4];
#pragma unroll
        for (int i = 0; i < 4; ++i) {
            a0[i] = *(const bf16x8*)(cA + aoff0 + i * 2048);   // row +16 each
            a1[i] = *(const bf16x8*)(cA + aoff1 + i * 2048);
            b0[i] = *(const bf16x8*)(cB + boff0 + i * 2048);
            b1[i] = *(const bf16x8*)(cB + boff1 + i * 2048);
        }
#pragma unroll
        for (int i = 0; i < 4; ++i)
#pragma unroll
            for (int j = 0; j < 4; ++j) {
                acc[i][j] = MFMA16(a0[i], b0[j], acc[i][j]);
                acc[i][j] = MFMA16(a1[i], b1[j], acc[i][j]);
            }
        __syncthreads();   // drains next-tile vmcnt + WAR on cur buffer
    }
}

// ---------------- encoder GEMM + relu (+RoPE / *old), 128² + coalesced ------
// (R15-proven verbatim) MODE 0: xs=relu(C), qr=rope(xs). MODE 1: xs*=relu(C)
template <int MODE>
__global__ __launch_bounds__(256) void enc_mfma_k(const bf16* __restrict__ A,
                                                  const bf16* __restrict__ Wt,
                                                  bf16* __restrict__ xs,
                                                  bf16* __restrict__ qr,
                                                  const bf16* __restrict__ cosH,
                                                  const bf16* __restrict__ sinH,
                                                  int aHeadStride) {
    __shared__ __align__(16) bf16 smem[32768];     // 64 KB (core), reused as Ot
    bf16 (*Ot)[136] = (bf16(*)[136])smem;          // 128x136 bf16 = 34,816 B
    int h = blockIdx.z;
    int row0 = blockIdx.y * 128, col0 = blockIdx.x * 128;
    const bf16* Ap = A + (size_t)h * aHeadStride + (size_t)row0 * D;
    const bf16* Bp = Wt + ((size_t)h * NN + col0) * D;
    int tid = threadIdx.x;
    f32x4 acc[4][4];
#pragma unroll
    for (int i = 0; i < 4; ++i)
#pragma unroll
        for (int j = 0; j < 4; ++j) acc[i][j] = f32x4{0.f, 0.f, 0.f, 0.f};
    gemm_core128v2(Ap, D, Bp, D, D / 64, smem, acc, tid);
    // core ends with __syncthreads(): LDS free for reuse

    int lane = tid & 63, wid = tid >> 6;
    int wr = (wid >> 1) * 64, wc = (wid & 1) * 64;
    int fr = lane & 15, fq = lane >> 4;
    // ---- stage relu tile ----
#pragma unroll
    for (int mi = 0; mi < 4; ++mi)
#pragma unroll
        for (int ni = 0; ni < 4; ++ni)
#pragma unroll
            for (int j = 0; j < 4; ++j)
                Ot[wr + mi * 16 + fq * 4 + j][wc + ni * 16 + fr] =
                    (bf16)fmaxf((float)acc[mi][ni][j], 0.0f);
    __syncthreads();
    int rrow = tid >> 4;             // 0..15
    int cb = (tid & 15) * 8;         // elem col (16B chunks)
    if (MODE == 0) {
        // coalesced xs stores: 8 passes x 16B/lane
#pragma unroll
        for (int p = 0; p < 8; ++p) {
            int row = p * 16 + rrow;
            *(bf16x8*)(xs + ((size_t)h * T + row0 + row) * NN + col0 + cb) =
                *(const bf16x8*)&Ot[row][cb];
        }
        __syncthreads();
        // ---- stage rope tile (reuse Ot) ----
#pragma unroll
        for (int mi = 0; mi < 4; ++mi)
#pragma unroll
            for (int ni = 0; ni < 4; ++ni)
#pragma unroll
                for (int j = 0; j < 4; ++j) {
                    float v = fmaxf((float)acc[mi][ni][j], 0.0f);
                    float pv = __shfl_xor(v, 1, 64);       // partner col n^1
                    int m = row0 + wr + mi * 16 + fq * 4 + j;
                    int n = col0 + wc + ni * 16 + fr;
                    float cs = (float)cosH[(size_t)m * (NN / 2) + (n >> 1)];
                    float sn = (float)sinH[(size_t)m * (NN / 2) + (n >> 1)];
                    Ot[wr + mi * 16 + fq * 4 + j][wc + ni * 16 + fr] =
                        (bf16)(v * cs + ((n & 1) ? pv * sn : -pv * sn));
                }
        __syncthreads();
#pragma unroll
        for (int p = 0; p < 8; ++p) {
            int row = p * 16 + rrow;
            *(bf16x8*)(qr + ((size_t)h * T + row0 + row) * NN + col0 + cb) =
                *(const bf16x8*)&Ot[row][cb];
        }
    } else {
        // coalesced read-modify-write of xs
#pragma unroll
        for (int p = 0; p < 8; ++p) {
            int row = p * 16 + rrow;
            size_t gb = ((size_t)h * T + row0 + row) * NN + col0 + cb;
            bf16x8 o = *(const bf16x8*)&Ot[row][cb];
            bf16x8 xv = *(const bf16x8*)(xs + gb);
            bf16x8 r;
#pragma unroll
            for (int k = 0; k < 8; ++k)
                r[k] = (bf16)((float)o[k] * (float)xv[k]);
            *(bf16x8*)(xs + gb) = r;
        }
    }
}

// ---------------- scores GEMM: spartb[ks][h][t][s] bf16 (lower-tri tiles) ---
// (R13-proven) 1-D grid, 576 blocks: bid%16 = (h,ksplit) group
__global__ __launch_bounds__(256) void qq_mfma_k(const bf16* __restrict__ qrb,
                                                 bf16* __restrict__ spartb) {
    __shared__ __align__(16) char smem[32768];
    int g = blockIdx.x & 15;          // (h, ksplit) group
    int h = g >> 2, ksplit = g & 3;
    int p = blockIdx.x >> 4;          // 0..35 -> (ti,tj), tj<=ti
    int ti = 0, accu = 0;
    while (accu + ti + 1 <= p) { ++ti; accu += ti; }
    int tj = p - accu;
    const bf16* Q = qrb + (size_t)h * T * NN + (size_t)ksplit * (NN / QKS);
    const bf16* Ap = Q + (size_t)(ti * 64) * NN;
    const bf16* Bp = Q + (size_t)(tj * 64) * NN;
    int tid = threadIdx.x;
    f32x4 acc[2][2];
#pragma unroll
    for (int i = 0; i < 2; ++i)
#pragma unroll
        for (int j = 0; j < 2; ++j) acc[i][j] = f32x4{0.f, 0.f, 0.f, 0.f};
    gemm_core64(Ap, NN, Bp, NN, (NN / QKS) / 64, (bf16*)smem, acc, tid);

    int lane = tid & 63, wid = tid >> 6;
    int wr = (wid >> 1) * 32, wc = (wid & 1) * 32;
    int fr = lane & 15, fq = lane >> 4;
    bf16* outp = spartb + (size_t)(ksplit * H + h) * T * T;
#pragma unroll
    for (int mi = 0; mi < 2; ++mi)
#pragma unroll
        for (int ni = 0; ni < 2; ++ni) {
            int s = tj * 64 + wc + ni * 16 + fr;
            int mbase = ti * 64 + wr + mi * 16 + fq * 4;
#pragma unroll
            for (int j = 0; j < 4; ++j)
                outp[(size_t)(mbase + j) * T + s] = (bf16)acc[mi][ni][j];
        }
}

// ---------------- sb[h][t][s] = bf16(sum_ks spartb), strict causal mask -----
__global__ __launch_bounds__(256) void mask_cvt_k(const bf16* __restrict__ spartb,
                                                  bf16* __restrict__ sb) {
    int t = blockIdx.x * 2 + (threadIdx.x >> 7);
    int h = blockIdx.y;
    int l = threadIdx.x & 127;
    int s = l * 4;
    const bf16* s0 = spartb + ((size_t)h * T + t) * T + s;
    const size_t st = (size_t)H * T * T;
    float a0 = 0, a1 = 0, a2 = 0, a3 = 0;
#pragma unroll
    for (int k = 0; k < QKS; ++k) {
        bf16x4 w = *(const bf16x4*)(s0 + k * st);
        a0 += (float)w[0]; a1 += (float)w[1]; a2 += (float)w[2]; a3 += (float)w[3];
    }
    bf16x4 o;
    o[0] = (bf16)((s + 0 < t) ? a0 : 0.0f);
    o[1] = (bf16)((s + 1 < t) ? a1 : 0.0f);
    o[2] = (bf16)((s + 2 < t) ? a2 : 0.0f);
    o[3] = (bf16)((s + 3 < t) ? a3 : 0.0f);
    *(bf16x4*)(sb + ((size_t)h * T + t) * T + s) = o;
}

// ---------------- av: ykv_pre[h][t][d] = sum_s sb[t,s] * x[s,d] (MFMA) ------
__global__ __launch_bounds__(256) void av_mfma_k(const bf16* __restrict__ sb,
                                                 const bf16* __restrict__ xbT,
                                                 float* __restrict__ ykv_pre) {
    __shared__ __align__(16) char smem[32768];
    int h = blockIdx.z;
    int ti = blockIdx.y;
    int row0 = ti * 64, col0 = blockIdx.x * 64;
    const bf16* Ap = sb + ((size_t)h * T + row0) * T;
    const bf16* Bp = xbT + (size_t)col0 * T;
    int tid = threadIdx.x;
    f32x4 acc[2][2];
#pragma unroll
    for (int i = 0; i < 2; ++i)
#pragma unroll
        for (int j = 0; j < 2; ++j) acc[i][j] = f32x4{0.f, 0.f, 0.f, 0.f};
    // causal: sb[t][s]==0 for s>=t, so only need k < (ti+1)*64
    gemm_core64(Ap, T, Bp, T, ti + 1, (bf16*)smem, acc, tid);

    int lane = tid & 63, wid = tid >> 6;
    int wr = (wid >> 1) * 32, wc = (wid & 1) * 32;
    int fr = lane & 15, fq = lane >> 4;
#pragma unroll
    for (int mi = 0; mi < 2; ++mi)
#pragma unroll
        for (int ni = 0; ni < 2; ++ni) {
            int n = col0 + wc + ni * 16 + fr;
            int mbase = row0 + wr + mi * 16 + fq * 4;
#pragma unroll
            for (int j = 0; j < 4; ++j)
                ykv_pre[((size_t)h * T + (mbase + j)) * D + n] = acc[mi][ni][j];
        }
}

// ---------------- ykv LN: ykvb = LN(ykv_pre) --------------------------------
__global__ __launch_bounds__(256) void ykv_ln_k(const float* __restrict__ ykv_pre,
                                                bf16* __restrict__ ykvb) {
    __shared__ float red[4];
    int t = blockIdx.x, h = blockIdx.y, d = threadIdx.x;
    float a = ykv_pre[((size_t)h * T + t) * D + d];
    float m = blk_sum256(a, red) * (1.0f / D);
    float df = a - m;
    float vv = blk_sum256(df * df, red) * (1.0f / D);
    ykvb[((size_t)h * T + t) * D + d] = (bf16)(df * rsqrtf(vv + EPSF));
}

// ---------------- decoder GEMM (split-K=16, 64x64 tiles, bf16 partials) -----
// 1-D grid, 512 blocks: ks = bid%16
__global__ __launch_bounds__(256) void dec_mfma_k(const bf16* __restrict__ xyb,
                                                  const bf16* __restrict__ decT,
                                                  bf16* __restrict__ ypartb) {
    __shared__ __align__(16) char smem[32768];
    int ks = blockIdx.x & 15;
    int t  = blockIdx.x >> 4;          // 0..31: col = t&3, row = t>>2
    int col0 = (t & 3) * 64, row0 = (t >> 2) * 64;
    int cbeg = ks * ((H * NN) / DSPLIT);   // 2048-wide slices, within one head
    int h = cbeg >> 13, n0 = cbeg & (NN - 1);
    const bf16* Ap = xyb + ((size_t)h * T + row0) * NN + n0;
    const bf16* Bp = decT + (size_t)col0 * (H * NN) + cbeg;
    int tid = threadIdx.x;
    f32x4 acc[2][2];
#pragma unroll
    for (int i = 0; i < 2; ++i)
#pragma unroll
        for (int j = 0; j < 2; ++j) acc[i][j] = f32x4{0.f, 0.f, 0.f, 0.f};
    gemm_core64(Ap, NN, Bp, H * NN, (H * NN / DSPLIT) / 64, (bf16*)smem, acc, tid);

    int lane = tid & 63, wid = tid >> 6;
    int wr = (wid >> 1) * 32, wc = (wid & 1) * 32;
    int fr = lane & 15, fq = lane >> 4;
#pragma unroll
    for (int mi = 0; mi < 2; ++mi)
#pragma unroll
        for (int ni = 0; ni < 2; ++ni) {
            int n = col0 + wc + ni * 16 + fr;
            int mbase = row0 + wr + mi * 16 + fq * 4;
#pragma unroll
            for (int j = 0; j < 4; ++j)
                ypartb[((size_t)ks * T + (mbase + j)) * D + n] = (bf16)acc[mi][ni][j];
        }
}

// ---------------- y = LN(sum ypartb); x = LN(x + y); bf16 + bf16^T copies ---
__global__ __launch_bounds__(256) void final_ln_k(const bf16* __restrict__ ypartb,
                                                  float* __restrict__ x,
                                                  bf16* __restrict__ xb,
                                                  bf16* __restrict__ xbT) {
    __shared__ float red[4];
    int t = blockIdx.x, d = threadIdx.x;
    float ys = 0.0f;
#pragma unroll
    for (int ks = 0; ks < DSPLIT; ++ks)
        ys += (float)ypartb[((size_t)ks * T + t) * D + d];
    float m = blk_sum256(ys, red) * (1.0f / D);
    float df = ys - m;
    float vv = blk_sum256(df * df, red) * (1.0f / D);
    float yln = df * rsqrtf(vv + EPSF);
    float val = x[(size_t)t * D + d] + yln;
    float m2 = blk_sum256(val, red) * (1.0f / D);
    float df2 = val - m2;
    float v2 = blk_sum256(df2 * df2, red) * (1.0f / D);
    float r = df2 * rsqrtf(v2 + EPSF);
    x[(size_t)t * D + d] = r;
    xb[(size_t)t * D + d] = (bf16)r;
    xbT[(size_t)d * T + t] = (bf16)r;
}

// ---------------- logits = x @ lm_head (f32) --------------------------------
__global__ __launch_bounds__(256) void logits_k(const float* __restrict__ x,
                                                const float* __restrict__ lm,
                                                float* __restrict__ out) {
    int t = blockIdx.x, v = threadIdx.x;
    float a = 0.0f;
    for (int d = 0; d < D; ++d)
        a = fmaf(x[(size_t)t * D + d], lm[(size_t)d * V + v], a);
    out[(size_t)t * V + v] = a;
}

extern "C" void kernel_launch(void* const* d_in, const int* in_sizes, int n_in,
                              void* d_out, int out_size, void* d_ws, size_t ws_size,
                              hipStream_t stream) {
    const int*   idx       = (const int*)d_in[0];
    const float* embed     = (const float*)d_in[1];
    const float* encoder   = (const float*)d_in[2];
    const float* encoder_v = (const float*)d_in[3];
    const float* decoder   = (const float*)d_in[4];
    const float* lm_head   = (const float*)d_in[5];
    float* out = (float*)d_out;

    // ---- workspace layout (146.8 MB — identical to passing R15) ----
    char* W = (char*)d_ws;
    float* x       = (float*)W; W += (size_t)T * D * 4;
    float* scratch = (float*)W; W += (size_t)QKS * H * T * T * 4;  // spartb / ykv_pre / ypartb union
    bf16* xb    = (bf16*)W; W += (size_t)T * D * 2;
    bf16* xbT   = (bf16*)W; W += (size_t)D * T * 2;
    bf16* sb    = (bf16*)W; W += (size_t)H * T * T * 2;
    bf16* ykvb  = (bf16*)W; W += (size_t)H * T * D * 2;
    bf16* encT  = (bf16*)W; W += (size_t)H * NN * D * 2;
    bf16* encVT = (bf16*)W; W += (size_t)H * NN * D * 2;
    bf16* decT  = (bf16*)W; W += (size_t)D * H * NN * 2;
    bf16* cosH  = (bf16*)W; W += (size_t)T * (NN / 2) * 2;
    bf16* sinH  = (bf16*)W; W += (size_t)T * (NN / 2) * 2;
    bf16* xs    = (bf16*)W; W += (size_t)H * T * NN * 2;
    bf16* qr    = (bf16*)W; W += (size_t)H * T * NN * 2;
    bf16* spartb = (bf16*)scratch;   // bf16 aliases of the scratch union
    bf16* ypartb = (bf16*)scratch;

    // ---- one-time per launch: weight transpose+convert, RoPE tables ----
    tcvt_k<<<dim3(NN / 32, D / 32, H), 256, 0, stream>>>(encoder, encT, D, NN);
    tcvt_k<<<dim3(NN / 32, D / 32, H), 256, 0, stream>>>(encoder_v, encVT, D, NN);
    tcvt_k<<<dim3(D / 32, (H * NN) / 32, 1), 256, 0, stream>>>(decoder, decT, H * NN, D);
    rope_tab_k<<<dim3((NN / 2) / 256, T), 256, 0, stream>>>(cosH, sinH);

    embed_ln_k<<<T, 256, 0, stream>>>(idx, embed, x, xb, xbT);

    for (int layer = 0; layer < N_LAYER; ++layer) {
        enc_mfma_k<0><<<dim3(NN / 128, T / 128, H), 256, 0, stream>>>(
            xb, encT, xs, qr, cosH, sinH, 0);
        qq_mfma_k<<<576, 256, 0, stream>>>(qr, spartb);
        mask_cvt_k<<<dim3(T / 2, H), 256, 0, stream>>>(spartb, sb);
        av_mfma_k<<<dim3(D / 64, T / 64, H), 256, 0, stream>>>(sb, xbT, scratch);
        ykv_ln_k<<<dim3(T, H), 256, 0, stream>>>(scratch, ykvb);
        enc_mfma_k<1><<<dim3(NN / 128, T / 128, H), 256, 0, stream>>>(
            ykvb, encVT, xs, nullptr, nullptr, nullptr, T * D);
        dec_mfma_k<<<512, 256, 0, stream>>>(xs, decT, ypartb);
        final_ln_k<<<T, 256, 0, stream>>>(ypartb, x, xb, xbT);
    }

    logits_k<<<T, 256, 0, stream>>>(x, lm_head, out);
}